// Round 1
// 179.769 us; speedup vs baseline: 1.4781x; 1.4781x over previous
//
#include <hip/hip_runtime.h>
#include <math.h>

#define B_N 65536
#define K_N 1024
#define D_N 256
#define CAPW 512
#define NWV 8            // waves per block (512 threads, 128 rows/block)

typedef __attribute__((ext_vector_type(8))) short bf16x8;
typedef __attribute__((ext_vector_type(4))) float f32x4;

// RNE float -> bf16 bits
__device__ __forceinline__ unsigned short f2bf(float f) {
    unsigned u = __float_as_uint(f);
    return (unsigned short)((u + 0x7FFFu + ((u >> 16) & 1u)) >> 16);
}
// monotone float <-> u32 order encoding
__device__ __forceinline__ unsigned encf(float f) {
    unsigned u = __float_as_uint(f);
    return u ^ ((unsigned)((int)u >> 31) | 0x80000000u);
}
__device__ __forceinline__ float decf(unsigned e) {
    unsigned u = (e & 0x80000000u) ? (e ^ 0x80000000u) : ~e;
    return __uint_as_float(u);
}
__device__ __forceinline__ void gload_lds16(const void* g, void* l) {
    __builtin_amdgcn_global_load_lds(
        (const __attribute__((address_space(1))) unsigned int*)g,
        (__attribute__((address_space(3))) unsigned int*)l, 16, 0, 0);
}

// THE exact dot chain (bit-identical to the chain validated rounds 1-5/8/11).
__device__ __forceinline__ float chain_dot(const float* __restrict__ zp,
                                           const float* __restrict__ wp) {
    float acc = 0.0f;
    #pragma unroll 1
    for (int j = 0; j < 64; ++j) {
        float4 za = *reinterpret_cast<const float4*>(zp + (j << 2));
        float4 wa = *reinterpret_cast<const float4*>(wp + (j << 2));
        acc = fmaf(za.x, wa.x, acc);
        acc = fmaf(za.y, wa.y, acc);
        acc = fmaf(za.z, wa.z, acc);
        acc = fmaf(za.w, wa.w, acc);
    }
    return acc;
}

// ---------------------------------------------------------------------------
// MFMA decode probe (validated rounds 8-11). flag: 0=H1, 1=swapped, 2=bad.
// ---------------------------------------------------------------------------
__device__ __forceinline__ int pA(int i, int k) {
    return ((i + k) & 15) - 7 + 9 * ((k >> 4) & 1);
}
__device__ __forceinline__ int pB(int j, int k) {
    return ((j + 3 * k) & 15) - 7 + 5 * ((k >> 4) & 1);
}

__global__ void mfma_probe_kernel(int* __restrict__ flag) {
    const int l = threadIdx.x & 63;
    const int c15 = l & 15, g = l >> 4;
    bf16x8 afr[8], bfr[8];
    #pragma unroll
    for (int m = 0; m < 8; ++m)
        #pragma unroll
        for (int e = 0; e < 8; ++e) {
            const int k = m * 32 + g * 8 + e;
            afr[m][e] = (short)f2bf((float)pA(c15, k));
            bfr[m][e] = (short)f2bf((float)pB(c15, k));
        }
    f32x4 acc = {0.f, 0.f, 0.f, 0.f};
    #pragma unroll
    for (int m = 0; m < 8; ++m)
        acc = __builtin_amdgcn_mfma_f32_16x16x32_bf16(afr[m], bfr[m], acc, 0, 0, 0);
    int h1 = 1, h2 = 1;
    #pragma unroll 1
    for (int reg = 0; reg < 4; ++reg) {
        const int q = 4 * g + reg;
        int e1 = 0, e2 = 0;
        for (int k = 0; k < 32; ++k) {        // patterns are 32-periodic in k
            e1 += pA(q, k) * pB(c15, k);
            e2 += pA(c15, k) * pB(q, k);
        }
        e1 *= 8; e2 *= 8;
        if (acc[reg] != (float)e1) h1 = 0;
        if (acc[reg] != (float)e2) h2 = 0;
    }
    h1 = __all(h1); h2 = __all(h2);
    if (threadIdx.x == 0) *flag = h1 ? 0 : (h2 ? 1 : 2);
}

// ---------------------------------------------------------------------------
// ww (validated tree) + bf16 codebook re-tiled for linear LDS fragment reads
// (validated r10/r11 layout).
// ---------------------------------------------------------------------------
__global__ void wprep_kernel(const float* __restrict__ w,
                             float* __restrict__ ww,
                             unsigned short* __restrict__ wb) {
    int wave = (int)((blockIdx.x * blockDim.x + threadIdx.x) >> 6);
    int lane = threadIdx.x & 63;
    if (wave >= K_N) return;
    const float4 v = *reinterpret_cast<const float4*>(w + ((size_t)wave << 8) + (lane << 2));
    float s = v.x * v.x + v.y * v.y + v.z * v.z + v.w * v.w;
    #pragma unroll
    for (int off = 32; off; off >>= 1) s += __shfl_xor(s, off, 64);
    if (lane == 0) ww[wave] = s;
    ushort4 b;
    b.x = f2bf(v.x); b.y = f2bf(v.y); b.z = f2bf(v.z); b.w = f2bf(v.w);
    const int mp = lane >> 3;
    const int gp = (lane >> 1) & 3;
    const int hp = (wave >> 4) & 1;
    const size_t off_b = (size_t)(wave >> 5) * 16384
        + (size_t)(((hp * 8 + mp) * 64 + gp * 16 + (wave & 15)) * 16)
        + (size_t)((lane & 1) * 8);
    *reinterpret_cast<ushort4*>((char*)wb + off_b) = b;
}

// ---------------------------------------------------------------------------
// Main kernel: single MFMA sweep, per-stage cross-lane ROW-min threshold sync,
// no stage-0 collection + stage-0 revisit with final threshold. Post-filtered
// exact rescore, fused gather + zq + loss.
//
// r12 geometry change: 8 waves/block (512 thr), 128 rows/block, grid = 512.
//   Rationale: old 1024-block grid at 3 blocks/CU resident ran as TWO batches
//   (768 @ 12 waves/CU, then 256 @ 4 waves/CU) -> measured Occ 22% matches
//   the (37.5+12.5)/2 model. 512 blocks = exactly 2/CU, all resident
//   (LDS 56,320 B -> 2 blocks/CU), one batch, 16 waves/CU.
// ---------------------------------------------------------------------------
__global__ __launch_bounds__(512, 4)
void vq_mfma_kernel(const float* __restrict__ z, const float* __restrict__ w,
                    const unsigned short* __restrict__ wb,
                    const float* __restrict__ ww,
                    const int* __restrict__ flagp,
                    float* __restrict__ zq_out,
                    float* __restrict__ idxf_out,
                    double* __restrict__ partial) {
    __shared__ alignas(16) short wbl[2][8192];   // 2 x 16KB stage buffers
    __shared__ float wwlds[1024];                //  4 KB
    __shared__ unsigned short rc[NWV][CAPW];     //  8 KB (row<<10 | code)
    __shared__ unsigned short dqv[NWV][CAPW];    //  8 KB (f16 of dist - zz)
    __shared__ float zz_l[NWV][16], band_l[NWV][16], thrm[NWV][16];
    __shared__ unsigned rowminU[NWV][16];
    __shared__ unsigned long long bestk[NWV][16];

    const int tid = threadIdx.x;
    const int wv = tid >> 6, l = tid & 63;
    const int c15 = l & 15, g = l >> 4;
    const int b0 = blockIdx.x << 7;              // 128 rows per block
    const int rbase = b0 + (wv << 4);
    const int flag = flagp[0];
    const bool fb0 = !(flag == 0 || flag == 1);

    // 512 threads x 2 x 16B = 16 KB stage (linear; per-wave contiguous dest)
#define STAGE(T, BUF) do {                                                    \
        const char* _s = (const char*)wb + (size_t)(T) * 16384 + tid * 16;    \
        char* _d = (char*)&wbl[BUF][0] + tid * 16;                            \
        gload_lds16(_s,         _d);                                          \
        gload_lds16(_s + 8192,  _d + 8192);                                   \
    } while (0)

    STAGE(0, 0);   // latency hides under the prologue

    if (l < 16) {
        rowminU[wv][l] = 0xFFFFFFFFu;
        bestk[wv][l]   = ~0ull;
    }
    reinterpret_cast<float2*>(wwlds)[tid] = reinterpret_cast<const float2*>(ww)[tid];

    // ---- per-row zz + band (bit-identical tree to validated rounds)
    #pragma unroll 1
    for (int r = 0; r < 16; ++r) {
        const float4 v = *reinterpret_cast<const float4*>(
            z + ((size_t)(rbase + r) << 8) + (l << 2));
        float s = v.x * v.x + v.y * v.y + v.z * v.z + v.w * v.w;
        float a = fabsf(v.x) + fabsf(v.y) + fabsf(v.z) + fabsf(v.w);
        #pragma unroll
        for (int off = 32; off; off >>= 1) {
            s += __shfl_xor(s, off, 64);
            a += __shfl_xor(a, off, 64);
        }
        if (l == 0) {
            zz_l[wv][r]   = s;
            band_l[wv][r] = a * 2.0e-5f + 1.0e-3f;   // >=2x rigorous bf16 bound
        }
    }

    bool fbw = fb0;
    int n = 0;

    int ml[4], cl[4];
    #pragma unroll
    for (int reg = 0; reg < 4; ++reg) {
        if (flag == 1) { ml[reg] = c15;          cl[reg] = 4 * g + reg; }
        else           { ml[reg] = 4 * g + reg;  cl[reg] = c15;         }
    }
    float zzv[4], bdv[4];
    #pragma unroll
    for (int reg = 0; reg < 4; ++reg) {
        zzv[reg] = zz_l[wv][ml[reg]];     // own-wave LDS, in-order
        bdv[reg] = band_l[wv][ml[reg]];
    }

    // A fragments: wave's 16 rows x 256 d, f32 -> bf16
    bf16x8 afr[8];
    {
        const float* zr = z + ((size_t)(rbase + c15) << 8) + (g << 3);
        #pragma unroll
        for (int m = 0; m < 8; ++m) {
            float4 lo = *reinterpret_cast<const float4*>(zr + (m << 5));
            float4 hi = *reinterpret_cast<const float4*>(zr + (m << 5) + 4);
            bf16x8 f;
            f[0] = (short)f2bf(lo.x); f[1] = (short)f2bf(lo.y);
            f[2] = (short)f2bf(lo.z); f[3] = (short)f2bf(lo.w);
            f[4] = (short)f2bf(hi.x); f[5] = (short)f2bf(hi.y);
            f[6] = (short)f2bf(hi.z); f[7] = (short)f2bf(hi.w);
            afr[m] = f;
        }
    }

    __syncthreads();   // stage 0 landed + all init visible

    float runmin[4] = {INFINITY, INFINITY, INFINITY, INFINITY};
    int base = 0;

    if (!fb0) {
        #pragma unroll 1
        for (int t = 0; t < 32; ++t) {
            if (t < 31) STAGE(t + 1, (t + 1) & 1);   // prefetch next stage

            const short* sb = wbl[t & 1];
            #pragma unroll
            for (int h = 0; h < 2; ++h) {
                f32x4 acc = {0.f, 0.f, 0.f, 0.f};
                #pragma unroll
                for (int m = 0; m < 8; ++m) {
                    bf16x8 bfr = *reinterpret_cast<const bf16x8*>(
                        &sb[((h * 8 + m) << 9) + (l << 3)]);   // linear: conflict-free
                    acc = __builtin_amdgcn_mfma_f32_16x16x32_bf16(afr[m], bfr, acc, 0, 0, 0);
                }
                #pragma unroll
                for (int reg = 0; reg < 4; ++reg) {
                    const int code = (t << 5) + (h << 4) + cl[reg];
                    const float dist = (zzv[reg] - 2.0f * acc[reg]) + wwlds[code];
                    if (t > 0) {    // stage 0: min-only (INF-threshold burst skipped)
                        const bool pred = (dist <= runmin[reg] + bdv[reg]);
                        const unsigned long long mask = __ballot(pred);
                        if (pred) {
                            const int slot = base + (int)__popcll(mask & ((1ull << l) - 1ull));
                            if (slot < CAPW) {
                                rc[wv][slot] = (unsigned short)((ml[reg] << 10) | code);
                                union { _Float16 h16; unsigned short u; } cv;
                                cv.h16 = (_Float16)(dist - zzv[reg]);
                                dqv[wv][slot] = cv.u;
                            }
                        }
                        base += (int)__popcll(mask);
                    }
                    runmin[reg] = fminf(runmin[reg], dist);
                }
            }

            // ---- cross-lane ROW-min sync: 16x faster threshold convergence
            if (flag == 1) {
                #pragma unroll
                for (int reg = 0; reg < 4; ++reg) {
                    runmin[reg] = fminf(runmin[reg], __shfl_xor(runmin[reg], 16, 64));
                    runmin[reg] = fminf(runmin[reg], __shfl_xor(runmin[reg], 32, 64));
                }
            } else {
                #pragma unroll
                for (int reg = 0; reg < 4; ++reg) {
                    runmin[reg] = fminf(runmin[reg], __shfl_xor(runmin[reg], 1, 64));
                    runmin[reg] = fminf(runmin[reg], __shfl_xor(runmin[reg], 2, 64));
                    runmin[reg] = fminf(runmin[reg], __shfl_xor(runmin[reg], 4, 64));
                    runmin[reg] = fminf(runmin[reg], __shfl_xor(runmin[reg], 8, 64));
                }
            }
            __syncthreads();   // drains next-stage DMA + releases buffer t&1
        }

        // ---- stage-0 revisit with the final (full-sweep) threshold
        STAGE(0, 0);
        __syncthreads();
        {
            const short* sb = wbl[0];
            #pragma unroll
            for (int h = 0; h < 2; ++h) {
                f32x4 acc = {0.f, 0.f, 0.f, 0.f};
                #pragma unroll
                for (int m = 0; m < 8; ++m) {
                    bf16x8 bfr = *reinterpret_cast<const bf16x8*>(
                        &sb[((h * 8 + m) << 9) + (l << 3)]);
                    acc = __builtin_amdgcn_mfma_f32_16x16x32_bf16(afr[m], bfr, acc, 0, 0, 0);
                }
                #pragma unroll
                for (int reg = 0; reg < 4; ++reg) {
                    const int code = (h << 4) + cl[reg];
                    const float dist = (zzv[reg] - 2.0f * acc[reg]) + wwlds[code];
                    const bool pred = (dist <= runmin[reg] + bdv[reg]);
                    const unsigned long long mask = __ballot(pred);
                    if (pred) {
                        const int slot = base + (int)__popcll(mask & ((1ull << l) - 1ull));
                        if (slot < CAPW) {
                            rc[wv][slot] = (unsigned short)((ml[reg] << 10) | code);
                            union { _Float16 h16; unsigned short u; } cv;
                            cv.h16 = (_Float16)(dist - zzv[reg]);
                            dqv[wv][slot] = cv.u;
                        }
                    }
                    base += (int)__popcll(mask);
                }
            }
        }

        n = base;
        if (n > CAPW) fbw = true;

        // per-row approx min -> post-filter threshold (own-wave, in-order)
        #pragma unroll
        for (int reg = 0; reg < 4; ++reg)
            atomicMin(&rowminU[wv][ml[reg]], encf(runmin[reg]));
        if (l < 16)
            thrm[wv][l] = (decf(rowminU[wv][l]) + band_l[wv][l]) - zz_l[wv][l] + 4.0e-4f;
    }
#undef STAGE

    // ---- post-filtered exact rescore (bit-identical chain) + consistency net
    if (!fbw) {
        int viol = 0;
        #pragma unroll 1
        for (int i = l; i < n; i += 64) {
            const int e = rc[wv][i];
            const int m = e >> 10, code = e & 1023;
            union { _Float16 h16; unsigned short u; } cv;
            cv.u = dqv[wv][i];
            const float dval = (float)cv.h16;
            if (dval <= thrm[wv][m]) {
                const float dot = chain_dot(z + ((size_t)(rbase + m) << 8),
                                            w + ((size_t)code << 8));
                const float dist = (zz_l[wv][m] - 2.0f * dot) + wwlds[code];
                if (fabsf((dval + zz_l[wv][m]) - dist) > band_l[wv][m] + 4.0e-4f)
                    viol = 1;
                atomicMin(&bestk[wv][m],
                          ((unsigned long long)encf(dist) << 32) | (unsigned)code);
            }
        }
        if (__any(viol)) fbw = true;
    }
    if (fbw) {
        // exhaustive exact fallback (bestk min over superset stays correct)
        #pragma unroll 1
        for (int m = 0; m < 16; ++m) {
            const float zzm = zz_l[wv][m];
            const float* zp = z + ((size_t)(rbase + m) << 8);
            for (int code = l; code < 1024; code += 64) {
                const float dist = (zzm - 2.0f * chain_dot(zp, w + ((size_t)code << 8)))
                                 + wwlds[code];
                atomicMin(&bestk[wv][m],
                          ((unsigned long long)encf(dist) << 32) | (unsigned)code);
            }
        }
    }

    // ---- indices out (ties: lowest code via packed key = numpy argmin)
    if (l < 16) {
        const int code = (int)(unsigned)(bestk[wv][l] & 0xFFFFFFFFull);
        idxf_out[rbase + l] = (float)code;
    }

    // ---- fused gather: zq write + per-block loss partial
    double s = 0.0;
    #pragma unroll 1
    for (int rr = 0; rr < 16; ++rr) {
        const int code = (int)(unsigned)(bestk[wv][rr] & 0xFFFFFFFFull);
        const float4 wv4 = *reinterpret_cast<const float4*>(
            w + ((size_t)code << 8) + (l << 2));
        const float4 zv4 = *reinterpret_cast<const float4*>(
            z + ((size_t)(rbase + rr) << 8) + (l << 2));
        *reinterpret_cast<float4*>(
            zq_out + ((size_t)(rbase + rr) << 8) + (l << 2)) = wv4;
        const float dx = wv4.x - zv4.x, dy = wv4.y - zv4.y;
        const float dz = wv4.z - zv4.z, dw = wv4.w - zv4.w;
        s += (double)dx * dx + (double)dy * dy + (double)dz * dz + (double)dw * dw;
    }
    __syncthreads();                         // all waves done with wbl
    double* sd = reinterpret_cast<double*>(&wbl[0][0]);   // overlay (4 KB of 16 KB)
    sd[tid] = s;
    __syncthreads();
    #pragma unroll
    for (int off = 256; off; off >>= 1) {
        if (tid < off) sd[tid] += sd[tid + off];
        __syncthreads();
    }
    if (tid == 0) partial[blockIdx.x] = sd[0];
}

// ---------------------------------------------------------------------------
__global__ void finalize_loss_kernel(const double* __restrict__ partial,
                                     float* __restrict__ out) {
    __shared__ double sd[256];
    const int t = threadIdx.x;
    double s = 0.0;
    for (int i = t; i < 512; i += 256) s += partial[i];
    sd[t] = s;
    __syncthreads();
    #pragma unroll
    for (int off = 128; off; off >>= 1) {
        if (t < off) sd[t] += sd[t + off];
        __syncthreads();
    }
    if (t == 0) {
        double mse = sd[0] / ((double)B_N * (double)D_N);
        out[0] = (float)(mse * 1.25);   // vq_loss = mse + 0.25*mse
    }
}

// ---------------------------------------------------------------------------
extern "C" void kernel_launch(void* const* d_in, const int* in_sizes, int n_in,
                              void* d_out, int out_size, void* d_ws, size_t ws_size,
                              hipStream_t stream) {
    const float* z = (const float*)d_in[0];   // [65536, 256]
    const float* w = (const float*)d_in[1];   // [1024, 256]

    float* out  = (float*)d_out;
    float* zq   = out;                        // [65536*256]
    float* loss = out + (size_t)B_N * D_N;    // [1]
    float* idxf = loss + 1;                   // [65536]

    // ws layout (well inside the proven 1,323,008-byte footprint)
    char* wsb = (char*)d_ws;
    float*          ww      = (float*)(wsb);                    //   4 KB @ 0
    unsigned short* wb      = (unsigned short*)(wsb + 4096);    // 512 KB
    int*            flag    = (int*)(wsb + 528384);             //   4 B
    double*         partial = (double*)(wsb + 528448);          //   4 KB (512)

    // 1. MFMA decode probe
    mfma_probe_kernel<<<1, 64, 0, stream>>>(flag);

    // 2. codebook prep: exact ww + re-tiled bf16 codebook
    wprep_kernel<<<K_N / 4, 256, 0, stream>>>(w, ww, wb);

    // 3. single-sweep MFMA filter + exact rescore + fused gather/loss
    //    8 waves/block, 128 rows/block, grid = 512 = exactly 2 blocks/CU
    vq_mfma_kernel<<<B_N / 128, 512, 0, stream>>>(z, w, wb, ww, flag,
                                                  zq, idxf, partial);

    // 4. finalize loss
    finalize_loss_kernel<<<1, 256, 0, stream>>>(partial, loss);
}

// Round 2
// 178.543 us; speedup vs baseline: 1.4883x; 1.0069x over previous
//
#include <hip/hip_runtime.h>
#include <math.h>

#define B_N 65536
#define K_N 1024
#define D_N 256
#define CAPW 512
#define NWV 8            // waves per block (512 threads, 128 rows/block)

typedef __attribute__((ext_vector_type(8))) short bf16x8;
typedef __attribute__((ext_vector_type(4))) float f32x4;

// RNE float -> bf16 bits
__device__ __forceinline__ unsigned short f2bf(float f) {
    unsigned u = __float_as_uint(f);
    return (unsigned short)((u + 0x7FFFu + ((u >> 16) & 1u)) >> 16);
}
// monotone float <-> u32 order encoding
__device__ __forceinline__ unsigned encf(float f) {
    unsigned u = __float_as_uint(f);
    return u ^ ((unsigned)((int)u >> 31) | 0x80000000u);
}
__device__ __forceinline__ float decf(unsigned e) {
    unsigned u = (e & 0x80000000u) ? (e ^ 0x80000000u) : ~e;
    return __uint_as_float(u);
}
__device__ __forceinline__ void gload_lds16(const void* g, void* l) {
    __builtin_amdgcn_global_load_lds(
        (const __attribute__((address_space(1))) unsigned int*)g,
        (__attribute__((address_space(3))) unsigned int*)l, 16, 0, 0);
}

// THE exact dot chain (bit-identical to the chain validated rounds 1-5/8/11).
__device__ __forceinline__ float chain_dot(const float* __restrict__ zp,
                                           const float* __restrict__ wp) {
    float acc = 0.0f;
    #pragma unroll 1
    for (int j = 0; j < 64; ++j) {
        float4 za = *reinterpret_cast<const float4*>(zp + (j << 2));
        float4 wa = *reinterpret_cast<const float4*>(wp + (j << 2));
        acc = fmaf(za.x, wa.x, acc);
        acc = fmaf(za.y, wa.y, acc);
        acc = fmaf(za.z, wa.z, acc);
        acc = fmaf(za.w, wa.w, acc);
    }
    return acc;
}

// ---------------------------------------------------------------------------
// MFMA decode probe (validated rounds 8-11). flag: 0=H1, 1=swapped, 2=bad.
// ---------------------------------------------------------------------------
__device__ __forceinline__ int pA(int i, int k) {
    return ((i + k) & 15) - 7 + 9 * ((k >> 4) & 1);
}
__device__ __forceinline__ int pB(int j, int k) {
    return ((j + 3 * k) & 15) - 7 + 5 * ((k >> 4) & 1);
}

__global__ void mfma_probe_kernel(int* __restrict__ flag) {
    const int l = threadIdx.x & 63;
    const int c15 = l & 15, g = l >> 4;
    bf16x8 afr[8], bfr[8];
    #pragma unroll
    for (int m = 0; m < 8; ++m)
        #pragma unroll
        for (int e = 0; e < 8; ++e) {
            const int k = m * 32 + g * 8 + e;
            afr[m][e] = (short)f2bf((float)pA(c15, k));
            bfr[m][e] = (short)f2bf((float)pB(c15, k));
        }
    f32x4 acc = {0.f, 0.f, 0.f, 0.f};
    #pragma unroll
    for (int m = 0; m < 8; ++m)
        acc = __builtin_amdgcn_mfma_f32_16x16x32_bf16(afr[m], bfr[m], acc, 0, 0, 0);
    int h1 = 1, h2 = 1;
    #pragma unroll 1
    for (int reg = 0; reg < 4; ++reg) {
        const int q = 4 * g + reg;
        int e1 = 0, e2 = 0;
        for (int k = 0; k < 32; ++k) {        // patterns are 32-periodic in k
            e1 += pA(q, k) * pB(c15, k);
            e2 += pA(c15, k) * pB(q, k);
        }
        e1 *= 8; e2 *= 8;
        if (acc[reg] != (float)e1) h1 = 0;
        if (acc[reg] != (float)e2) h2 = 0;
    }
    h1 = __all(h1); h2 = __all(h2);
    if (threadIdx.x == 0) *flag = h1 ? 0 : (h2 ? 1 : 2);
}

// ---------------------------------------------------------------------------
// ww (validated tree) + bf16 codebook re-tiled for linear LDS fragment reads
// (validated r10/r11 layout).
// ---------------------------------------------------------------------------
__global__ void wprep_kernel(const float* __restrict__ w,
                             float* __restrict__ ww,
                             unsigned short* __restrict__ wb) {
    int wave = (int)((blockIdx.x * blockDim.x + threadIdx.x) >> 6);
    int lane = threadIdx.x & 63;
    if (wave >= K_N) return;
    const float4 v = *reinterpret_cast<const float4*>(w + ((size_t)wave << 8) + (lane << 2));
    float s = v.x * v.x + v.y * v.y + v.z * v.z + v.w * v.w;
    #pragma unroll
    for (int off = 32; off; off >>= 1) s += __shfl_xor(s, off, 64);
    if (lane == 0) ww[wave] = s;
    ushort4 b;
    b.x = f2bf(v.x); b.y = f2bf(v.y); b.z = f2bf(v.z); b.w = f2bf(v.w);
    const int mp = lane >> 3;
    const int gp = (lane >> 1) & 3;
    const int hp = (wave >> 4) & 1;
    const size_t off_b = (size_t)(wave >> 5) * 16384
        + (size_t)(((hp * 8 + mp) * 64 + gp * 16 + (wave & 15)) * 16)
        + (size_t)((lane & 1) * 8);
    *reinterpret_cast<ushort4*>((char*)wb + off_b) = b;
}

// ---------------------------------------------------------------------------
// Main kernel.
// r13: 3-buffer counted-vmcnt pipeline (T3+T4): raw s_barrier + manual
//   s_waitcnt vmcnt(2) keeps the next-next stage's global_load_lds in flight
//   ACROSS the barrier (old __syncthreads forced vmcnt(0) drain 33x/block).
//   Stage-0 revisit folded into the loop as t=32 (src tile 0 -> buf[2]).
//   FIFO audit: pre-loop issues S0,S1 + full drain (__syncthreads).
//     iter t: issue S(t+2) -> buf[(t+2)%3]; compute buf[t%3];
//     end: vmcnt(2) drains S(t+1) (leaves S(t+2) in flight) + s_barrier.
//     Buffer written at t was last read at t-1, protected by t-1's barrier.
//   Also: prologue zz pass 8-row load batching (bit-identical per-row trees),
//   epilogue gather unroll 2.
// ---------------------------------------------------------------------------
__global__ __launch_bounds__(512, 4)
void vq_mfma_kernel(const float* __restrict__ z, const float* __restrict__ w,
                    const unsigned short* __restrict__ wb,
                    const float* __restrict__ ww,
                    const int* __restrict__ flagp,
                    float* __restrict__ zq_out,
                    float* __restrict__ idxf_out,
                    double* __restrict__ partial) {
    __shared__ alignas(16) short wbl[3][8192];   // 3 x 16KB stage buffers
    __shared__ float wwlds[1024];                //  4 KB
    __shared__ unsigned short rc[NWV][CAPW];     //  8 KB (row<<10 | code)
    __shared__ unsigned short dqv[NWV][CAPW];    //  8 KB (f16 of dist - zz)
    __shared__ float zz_l[NWV][16], band_l[NWV][16], thrm[NWV][16];
    __shared__ unsigned rowminU[NWV][16];
    __shared__ unsigned long long bestk[NWV][16];

    const int tid = threadIdx.x;
    const int wv = tid >> 6, l = tid & 63;
    const int c15 = l & 15, g = l >> 4;
    const int b0 = blockIdx.x << 7;              // 128 rows per block
    const int rbase = b0 + (wv << 4);
    const int flag = flagp[0];
    const bool fb0 = !(flag == 0 || flag == 1);

    // 512 threads x 2 x 16B = 16 KB stage (linear; per-wave contiguous dest)
#define STAGE(T, BUF) do {                                                    \
        const char* _s = (const char*)wb + (size_t)(T) * 16384 + tid * 16;    \
        char* _d = (char*)&wbl[BUF][0] + tid * 16;                            \
        gload_lds16(_s,         _d);                                          \
        gload_lds16(_s + 8192,  _d + 8192);                                   \
    } while (0)

    STAGE(0, 0);   // latency hides under the prologue

    if (l < 16) {
        rowminU[wv][l] = 0xFFFFFFFFu;
        bestk[wv][l]   = ~0ull;
    }
    reinterpret_cast<float2*>(wwlds)[tid] = reinterpret_cast<const float2*>(ww)[tid];

    // ---- per-row zz + band: 8-row load batches for memory ILP; the per-row
    //      arithmetic + shuffle tree is bit-identical to the validated rounds.
    #pragma unroll 1
    for (int half = 0; half < 2; ++half) {
        float4 vrow[8];
        #pragma unroll
        for (int r = 0; r < 8; ++r)
            vrow[r] = *reinterpret_cast<const float4*>(
                z + ((size_t)(rbase + half * 8 + r) << 8) + (l << 2));
        #pragma unroll
        for (int r = 0; r < 8; ++r) {
            const float4 v = vrow[r];
            float s = v.x * v.x + v.y * v.y + v.z * v.z + v.w * v.w;
            float a = fabsf(v.x) + fabsf(v.y) + fabsf(v.z) + fabsf(v.w);
            #pragma unroll
            for (int off = 32; off; off >>= 1) {
                s += __shfl_xor(s, off, 64);
                a += __shfl_xor(a, off, 64);
            }
            if (l == 0) {
                zz_l[wv][half * 8 + r]   = s;
                band_l[wv][half * 8 + r] = a * 2.0e-5f + 1.0e-3f;
            }
        }
    }

    STAGE(1, 1);   // second prefetch in flight before the first sync

    bool fbw = fb0;
    int n = 0;

    int ml[4], cl[4];
    #pragma unroll
    for (int reg = 0; reg < 4; ++reg) {
        if (flag == 1) { ml[reg] = c15;          cl[reg] = 4 * g + reg; }
        else           { ml[reg] = 4 * g + reg;  cl[reg] = c15;         }
    }

    // A fragments: wave's 16 rows x 256 d, f32 -> bf16
    bf16x8 afr[8];
    {
        const float* zr = z + ((size_t)(rbase + c15) << 8) + (g << 3);
        #pragma unroll
        for (int m = 0; m < 8; ++m) {
            float4 lo = *reinterpret_cast<const float4*>(zr + (m << 5));
            float4 hi = *reinterpret_cast<const float4*>(zr + (m << 5) + 4);
            bf16x8 f;
            f[0] = (short)f2bf(lo.x); f[1] = (short)f2bf(lo.y);
            f[2] = (short)f2bf(lo.z); f[3] = (short)f2bf(lo.w);
            f[4] = (short)f2bf(hi.x); f[5] = (short)f2bf(hi.y);
            f[6] = (short)f2bf(hi.z); f[7] = (short)f2bf(hi.w);
            afr[m] = f;
        }
    }

    __syncthreads();   // stages 0+1 landed + all init visible (full drain, once)

    float zzv[4], bdv[4];
    #pragma unroll
    for (int reg = 0; reg < 4; ++reg) {
        zzv[reg] = zz_l[wv][ml[reg]];     // own-wave LDS, in-order
        bdv[reg] = band_l[wv][ml[reg]];
    }

    float runmin[4] = {INFINITY, INFINITY, INFINITY, INFINITY};
    int base = 0;

    if (!fb0) {
        // 33 iterations: t=0..31 normal tiles, t=32 = stage-0 revisit.
        #pragma unroll 1
        for (int t = 0; t <= 32; ++t) {
            if (t + 2 <= 32) {
                const int st = (t + 2 <= 31) ? (t + 2) : 0;   // 32 -> tile 0
                STAGE(st, (t + 2) % 3);
            }

            const short* sb = wbl[t % 3];
            const int tc = (t <= 31) ? t : 0;                 // code base for revisit
            #pragma unroll
            for (int h = 0; h < 2; ++h) {
                f32x4 acc = {0.f, 0.f, 0.f, 0.f};
                #pragma unroll
                for (int m = 0; m < 8; ++m) {
                    bf16x8 bfr = *reinterpret_cast<const bf16x8*>(
                        &sb[((h * 8 + m) << 9) + (l << 3)]);   // linear: conflict-free
                    acc = __builtin_amdgcn_mfma_f32_16x16x32_bf16(afr[m], bfr, acc, 0, 0, 0);
                }
                #pragma unroll
                for (int reg = 0; reg < 4; ++reg) {
                    const int code = (tc << 5) + (h << 4) + cl[reg];
                    const float dist = (zzv[reg] - 2.0f * acc[reg]) + wwlds[code];
                    if (t > 0) {    // t=0: min-only; 1..31: collect; 32: revisit-collect
                        const bool pred = (dist <= runmin[reg] + bdv[reg]);
                        const unsigned long long mask = __ballot(pred);
                        if (pred) {
                            const int slot = base + (int)__popcll(mask & ((1ull << l) - 1ull));
                            if (slot < CAPW) {
                                rc[wv][slot] = (unsigned short)((ml[reg] << 10) | code);
                                union { _Float16 h16; unsigned short u; } cv;
                                cv.h16 = (_Float16)(dist - zzv[reg]);
                                dqv[wv][slot] = cv.u;
                            }
                        }
                        base += (int)__popcll(mask);
                    }
                    if (t < 32) runmin[reg] = fminf(runmin[reg], dist);
                }
            }

            if (t < 32) {
                // ---- cross-lane ROW-min sync: 16x faster threshold convergence
                if (flag == 1) {
                    #pragma unroll
                    for (int reg = 0; reg < 4; ++reg) {
                        runmin[reg] = fminf(runmin[reg], __shfl_xor(runmin[reg], 16, 64));
                        runmin[reg] = fminf(runmin[reg], __shfl_xor(runmin[reg], 32, 64));
                    }
                } else {
                    #pragma unroll
                    for (int reg = 0; reg < 4; ++reg) {
                        runmin[reg] = fminf(runmin[reg], __shfl_xor(runmin[reg], 1, 64));
                        runmin[reg] = fminf(runmin[reg], __shfl_xor(runmin[reg], 2, 64));
                        runmin[reg] = fminf(runmin[reg], __shfl_xor(runmin[reg], 4, 64));
                        runmin[reg] = fminf(runmin[reg], __shfl_xor(runmin[reg], 8, 64));
                    }
                }
                // ---- counted-vmcnt barrier: drain S(t+1), keep S(t+2) in flight
                if (t + 2 <= 32) {
                    asm volatile("s_waitcnt vmcnt(2) lgkmcnt(0)" ::: "memory");
                } else {
                    asm volatile("s_waitcnt vmcnt(0) lgkmcnt(0)" ::: "memory");
                }
                __builtin_amdgcn_sched_barrier(0);
                __builtin_amdgcn_s_barrier();
                __builtin_amdgcn_sched_barrier(0);
            }
        }

        n = base;
        if (n > CAPW) fbw = true;

        // per-row approx min -> post-filter threshold (own-wave, in-order)
        #pragma unroll
        for (int reg = 0; reg < 4; ++reg)
            atomicMin(&rowminU[wv][ml[reg]], encf(runmin[reg]));
        if (l < 16)
            thrm[wv][l] = (decf(rowminU[wv][l]) + band_l[wv][l]) - zz_l[wv][l] + 4.0e-4f;
    }
#undef STAGE

    // ---- post-filtered exact rescore (bit-identical chain) + consistency net
    if (!fbw) {
        int viol = 0;
        #pragma unroll 1
        for (int i = l; i < n; i += 64) {
            const int e = rc[wv][i];
            const int m = e >> 10, code = e & 1023;
            union { _Float16 h16; unsigned short u; } cv;
            cv.u = dqv[wv][i];
            const float dval = (float)cv.h16;
            if (dval <= thrm[wv][m]) {
                const float dot = chain_dot(z + ((size_t)(rbase + m) << 8),
                                            w + ((size_t)code << 8));
                const float dist = (zz_l[wv][m] - 2.0f * dot) + wwlds[code];
                if (fabsf((dval + zz_l[wv][m]) - dist) > band_l[wv][m] + 4.0e-4f)
                    viol = 1;
                atomicMin(&bestk[wv][m],
                          ((unsigned long long)encf(dist) << 32) | (unsigned)code);
            }
        }
        if (__any(viol)) fbw = true;
    }
    if (fbw) {
        // exhaustive exact fallback (bestk min over superset stays correct)
        #pragma unroll 1
        for (int m = 0; m < 16; ++m) {
            const float zzm = zz_l[wv][m];
            const float* zp = z + ((size_t)(rbase + m) << 8);
            for (int code = l; code < 1024; code += 64) {
                const float dist = (zzm - 2.0f * chain_dot(zp, w + ((size_t)code << 8)))
                                 + wwlds[code];
                atomicMin(&bestk[wv][m],
                          ((unsigned long long)encf(dist) << 32) | (unsigned)code);
            }
        }
    }

    // ---- indices out (ties: lowest code via packed key = numpy argmin)
    if (l < 16) {
        const int code = (int)(unsigned)(bestk[wv][l] & 0xFFFFFFFFull);
        idxf_out[rbase + l] = (float)code;
    }

    // ---- fused gather: zq write + per-block loss partial
    int codes[16];
    #pragma unroll
    for (int rr = 0; rr < 16; ++rr)
        codes[rr] = (int)(unsigned)(bestk[wv][rr] & 0xFFFFFFFFull);
    double s = 0.0;
    #pragma unroll 2
    for (int rr = 0; rr < 16; ++rr) {
        const int code = codes[rr];
        const float4 wv4 = *reinterpret_cast<const float4*>(
            w + ((size_t)code << 8) + (l << 2));
        const float4 zv4 = *reinterpret_cast<const float4*>(
            z + ((size_t)(rbase + rr) << 8) + (l << 2));
        *reinterpret_cast<float4*>(
            zq_out + ((size_t)(rbase + rr) << 8) + (l << 2)) = wv4;
        const float dx = wv4.x - zv4.x, dy = wv4.y - zv4.y;
        const float dz = wv4.z - zv4.z, dw = wv4.w - zv4.w;
        s += (double)dx * dx + (double)dy * dy + (double)dz * dz + (double)dw * dw;
    }
    __syncthreads();                         // all waves done with wbl (+ DMA drain)
    double* sd = reinterpret_cast<double*>(&wbl[0][0]);   // overlay (4 KB of 16 KB)
    sd[tid] = s;
    __syncthreads();
    #pragma unroll
    for (int off = 256; off; off >>= 1) {
        if (tid < off) sd[tid] += sd[tid + off];
        __syncthreads();
    }
    if (tid == 0) partial[blockIdx.x] = sd[0];
}

// ---------------------------------------------------------------------------
__global__ void finalize_loss_kernel(const double* __restrict__ partial,
                                     float* __restrict__ out) {
    __shared__ double sd[256];
    const int t = threadIdx.x;
    double s = 0.0;
    for (int i = t; i < 512; i += 256) s += partial[i];
    sd[t] = s;
    __syncthreads();
    #pragma unroll
    for (int off = 128; off; off >>= 1) {
        if (t < off) sd[t] += sd[t + off];
        __syncthreads();
    }
    if (t == 0) {
        double mse = sd[0] / ((double)B_N * (double)D_N);
        out[0] = (float)(mse * 1.25);   // vq_loss = mse + 0.25*mse
    }
}

// ---------------------------------------------------------------------------
extern "C" void kernel_launch(void* const* d_in, const int* in_sizes, int n_in,
                              void* d_out, int out_size, void* d_ws, size_t ws_size,
                              hipStream_t stream) {
    const float* z = (const float*)d_in[0];   // [65536, 256]
    const float* w = (const float*)d_in[1];   // [1024, 256]

    float* out  = (float*)d_out;
    float* zq   = out;                        // [65536*256]
    float* loss = out + (size_t)B_N * D_N;    // [1]
    float* idxf = loss + 1;                   // [65536]

    // ws layout (well inside the proven 1,323,008-byte footprint)
    char* wsb = (char*)d_ws;
    float*          ww      = (float*)(wsb);                    //   4 KB @ 0
    unsigned short* wb      = (unsigned short*)(wsb + 4096);    // 512 KB
    int*            flag    = (int*)(wsb + 528384);             //   4 B
    double*         partial = (double*)(wsb + 528448);          //   4 KB (512)

    // 1. MFMA decode probe
    mfma_probe_kernel<<<1, 64, 0, stream>>>(flag);

    // 2. codebook prep: exact ww + re-tiled bf16 codebook
    wprep_kernel<<<K_N / 4, 256, 0, stream>>>(w, ww, wb);

    // 3. single-sweep MFMA filter + exact rescore + fused gather/loss
    //    8 waves/block, 128 rows/block, grid = 512 = exactly 2 blocks/CU
    vq_mfma_kernel<<<B_N / 128, 512, 0, stream>>>(z, w, wb, ww, flag,
                                                  zq, idxf, partial);

    // 4. finalize loss
    finalize_loss_kernel<<<1, 256, 0, stream>>>(partial, loss);
}